// Round 5
// baseline (397.516 us; speedup 1.0000x reference)
//
#include <hip/hip_runtime.h>

// WindowAttention (Swin-3D) on MI355X / gfx950.
// R18 = R17 with inline-asm permlane swaps replaced by the official
// __builtin_amdgcn_permlane{32,16}_swap builtins (the only untested construct
// after two container failures). Recap: (1) qkv/proj GEMMs: 2-phase
// double-buffered pipeline (prefetch next K-tile via global_load_lds BEFORE
// compute, single barrier/iter) + per-wave barrier-free coalesced epilogue.
// (2) attn: P LDS round-trip replaced by permlane-swap in-register
// redistribution; V^T laid out [ktp][32ch][32key] (key-block XOR by ch>>3).
// LDS 45056 B => 3 blocks/CU; XCD-chunked block swizzle.

#define DIMD 384
#define NHH 12
#define HEADD 32
#define LL 343
#define NWW 64
#define NTOK (NWW * LL)            // 21952
#define MPT 176                    // m tiles (128 each)
#define MP (MPT * 128)             // 22528
#define LP 352                     // L padded to 22*16
#define QT 22
#define MW 12                      // mask words per query row (11 used)
#define SCALE_ 0.17677669529663687f
#define LOG2E_ 1.4426950408889634f
#define NEGBIG_ (-1.0e4f)

typedef _Float16 f16;
typedef _Float16 v8h __attribute__((ext_vector_type(8)));
typedef _Float16 v4h __attribute__((ext_vector_type(4)));
typedef float v4f __attribute__((ext_vector_type(4)));
typedef unsigned int v2u __attribute__((ext_vector_type(2)));

__device__ __forceinline__ void async_cp16(const void* g, void* l) {
    __builtin_amdgcn_global_load_lds(
        (const __attribute__((address_space(1))) void*)g,
        (__attribute__((address_space(3))) void*)l, 16, 0, 0);
}

__device__ __forceinline__ unsigned int pk2(float a, float b) {
    return __builtin_bit_cast(unsigned int, __builtin_amdgcn_cvt_pkrtz(a, b));
}

// ---- workspace layout (bytes) ----
constexpr size_t HBUF = (size_t)NHH * MP * HEADD * 2;          // per q/k/v
constexpr size_t OFF_Q    = 0;
constexpr size_t OFF_K    = OFF_Q  + HBUF;
constexpr size_t OFF_V    = OFF_K  + HBUF;
constexpr size_t OFF_AO   = OFF_V  + HBUF;                     // f16 [MP][384]; xh then AO
constexpr size_t OFF_BT   = OFF_AO + (size_t)MP * DIMD * 2;    // f32 biasT (NH,88,352,4) *log2e, key-major
constexpr size_t OFF_WT   = OFF_BT + (size_t)NHH * LP * LP * 4;
constexpr size_t OFF_PWT  = OFF_WT + (size_t)3 * DIMD * DIMD * 2;
constexpr size_t OFF_MTB  = OFF_PWT + (size_t)DIMD * DIMD * 2; // uint (NW, 352 queries, 12 key-words)

// attn LDS: Ks [352][32] + Vts [11][32][32]
constexpr int SMEM_ATTN = (LP * 32 + LP * 32) * 2;   // 45056

// ---------------- fused prep ----------------
#define S0 (NTOK * DIMD / 4)
#define S1 (3 * DIMD * DIMD)
#define S2 (DIMD * DIMD)
#define S3 (NHH * LP * LP)
#define S4 (NWW * MW * LP)
#define SPREP (S0 + S1 + S2 + S3 + S4)

__global__ __launch_bounds__(256) void prep_all(
    const float* __restrict__ x, f16* __restrict__ xh,
    const float* __restrict__ qkv_w, f16* __restrict__ wt,
    const float* __restrict__ proj_w, f16* __restrict__ pwt,
    const float* __restrict__ table, const int* __restrict__ rel, float* __restrict__ btf,
    const int* __restrict__ mask, unsigned int* __restrict__ mtb) {
    int t = blockIdx.x * 256 + threadIdx.x;
    if (t < S0) {
        float4 v = *(const float4*)(x + (size_t)t * 4);
        v4h o; o[0] = (f16)v.x; o[1] = (f16)v.y; o[2] = (f16)v.z; o[3] = (f16)v.w;
        *(v4h*)(xh + (size_t)t * 4) = o;
    } else if (t < S0 + S1) {
        int e = t - S0;
        int n = e / DIMD, k = e % DIMD;          // wt[n][k] = qkv_w[k][n]
        wt[e] = (f16)qkv_w[(size_t)k * (3 * DIMD) + n];
    } else if (t < S0 + S1 + S2) {
        int e = t - S0 - S1;
        int n = e / DIMD, k = e % DIMD;
        pwt[e] = (f16)proj_w[(size_t)k * DIMD + n];
    } else if (t < S0 + S1 + S2 + S3) {
        // biasT[h][kq][q][e2] = bias(h, query=q, key=kq*4+e2)*log2e, pads -> -1e4
        int e = t - S0 - S1 - S2;
        int h = e / (LP * LP), rem = e % (LP * LP);
        int kq = rem / (LP * 4);
        int rem2 = rem % (LP * 4);
        int col = rem2 >> 2, e2 = rem2 & 3;      // col = query
        int key = kq * 4 + e2;
        float v = NEGBIG_;
        if (col < LL && key < LL) v = table[(size_t)rel[col * LL + key] * NHH + h] * LOG2E_;
        btf[e] = v;
    } else if (t < SPREP) {
        // mtb[n][q][kw]: bit b = mask[n][query q][key kw*32+b]
        int e = t - S0 - S1 - S2 - S3;
        int n = e / (MW * LP), rem = e % (MW * LP);
        int q = rem / MW, kw = rem % MW;
        unsigned int wd = 0;
        if (q < LL && kw < 11) {
            int kbase = kw * 32;
            int kmax = LL - kbase; if (kmax > 32) kmax = 32;
            const int* mrow = mask + ((size_t)n * LL + q) * LL + kbase;
#pragma unroll 4
            for (int b = 0; b < kmax; ++b)
                if (mrow[b]) wd |= (1u << b);
        }
        mtb[((size_t)n * LP + q) * MW + kw] = wd;
    }
}

// ---------------- QKV GEMM (128x128, 2-phase dbuf pipeline, XCD swizzle) ----------------
__global__ __launch_bounds__(256) void qkv_gemm(
    const f16* __restrict__ xh, const f16* __restrict__ wt,
    f16* __restrict__ qb, f16* __restrict__ kb, f16* __restrict__ vb) {
    __shared__ f16 ABs[16384];       // 2 bufs x (A 128x32 + B 128x32)
    const int lin = blockIdx.x;
    const int m0 = ((lin / 72) * 8 + (lin & 7)) * 128;
    const int n0 = ((lin >> 3) % 9) * 128;
    const int tid = threadIdx.x;
    const int wave = tid >> 6, lane = tid & 63;
    const int quad = lane >> 4, l15 = lane & 15;
    const int wm = (wave >> 1) * 64, wn = (wave & 1) * 64;
    const int srow = lane >> 2, scol = (lane & 3) * 8;
    const f16* ga0 = xh + (size_t)(m0 + wave * 32 + srow) * DIMD + scol;
    const f16* ga1 = ga0 + (size_t)16 * DIMD;
    const f16* gb0 = wt + (size_t)(n0 + wave * 32 + srow) * DIMD + scol;
    const f16* gb1 = gb0 + (size_t)16 * DIMD;
    {
        f16* la = ABs + wave * 1024;
        async_cp16(ga0, la);
        async_cp16(ga1, la + 512);
        async_cp16(gb0, la + 4096);
        async_cp16(gb1, la + 4096 + 512);
    }
    __syncthreads();
    v4f acc[4][4] = {};
    for (int t = 0; t < 12; ++t) {
        const int cur = (t & 1) << 13;          // 0 / 8192 f16 flip
        if (t < 11) {                            // prefetch next tile: overlaps MFMA below
            const int nk = (t + 1) * 32;
            f16* la = ABs + (cur ^ 8192) + wave * 1024;
            async_cp16(ga0 + nk, la);
            async_cp16(ga1 + nk, la + 512);
            async_cp16(gb0 + nk, la + 4096);
            async_cp16(gb1 + nk, la + 4096 + 512);
        }
        const f16* As = ABs + cur;
        const f16* Bs = As + 4096;
        v8h a[4], b[4];
#pragma unroll
        for (int i = 0; i < 4; ++i) a[i] = *(const v8h*)(As + (wm + i * 16 + l15) * 32 + quad * 8);
#pragma unroll
        for (int j = 0; j < 4; ++j) b[j] = *(const v8h*)(Bs + (wn + j * 16 + l15) * 32 + quad * 8);
#pragma unroll
        for (int i = 0; i < 4; ++i)
#pragma unroll
            for (int j = 0; j < 4; ++j)
                acc[i][j] = __builtin_amdgcn_mfma_f32_16x16x32_f16(a[i], b[j], acc[i][j], 0, 0, 0);
        __syncthreads();                         // single barrier: drains prefetch (vmcnt0) + protects buf reuse
    }
    // epilogue: per-wave private LDS transpose, zero barriers, coalesced 16B stores
    const int t3 = n0 / DIMD;
    f16* dst = (t3 == 0) ? qb : (t3 == 1) ? kb : vb;
    const float sc = (t3 == 0) ? (SCALE_ * LOG2E_) : 1.0f;
    const int nrel = n0 - t3 * DIMD;
    f16* Cw = ABs + wave * (16 * 72);            // [16 rows][72 stride], wave-private
#pragma unroll
    for (int i = 0; i < 4; ++i) {
#pragma unroll
        for (int e = 0; e < 4; ++e)
#pragma unroll
            for (int j = 0; j < 4; ++j)
                Cw[(quad * 4 + e) * 72 + j * 16 + l15] = (f16)(acc[i][j][e] * sc);
        // same-wave DS ordering: no barrier needed
#pragma unroll
        for (int c = 0; c < 2; ++c) {
            int chunk = quad + c * 4;            // 0..7 -> 8-col piece
            int gm = m0 + wm + i * 16 + l15;
            int gcol = nrel + wn + chunk * 8;
            if (gm < NTOK) {
                size_t off = (size_t)(gcol >> 5) * ((size_t)MP * HEADD)
                           + (gcol & 31) + (size_t)gm * HEADD;
                *(v8h*)(dst + off) = *(const v8h*)(Cw + l15 * 72 + chunk * 8);
            }
        }
    }
}

// ---------------- attention (S^T tiles, reg-mask, permlane P, 3 blocks/CU) ----------------
__global__ __launch_bounds__(512, 6) void attn_kernel(
    const f16* __restrict__ qb, const f16* __restrict__ kb, const f16* __restrict__ vb,
    const float* __restrict__ biasT, const unsigned int* __restrict__ mtb,
    f16* __restrict__ ao) {
    extern __shared__ char smem[];
    f16* Ks  = (f16*)smem;            // [352 keys][32 ch], 16B-block XOR by (key&3)
    f16* Vts = Ks + LP * 32;          // [11 ktp][32 ch][32 keys], key-block XOR by (ch>>3)&3
    const int bid = blockIdx.x;
    // XCD-chunked swizzle: XCD x owns j2 in [96x, 96x+96) -> 1.5 head slices per XCD L2
    const int j2 = (bid & 7) * 96 + (bid >> 3);
    const int n = j2 & 63, h = j2 >> 6;
    const int tid = threadIdx.x, wave = tid >> 6, lane = tid & 63;
    const int quad = lane >> 4, l15 = lane & 15;
    const size_t slice = ((size_t)h * MP + n * LL) * HEADD;
    const f16* qg = qb + slice;
    const f16* kg = kb + slice;
    const f16* vg = vb + slice;
    // K staging: [key][32ch], swizzled 16B blocks, zero-pad keys >= LL
    for (int i = tid; i < LP * 4; i += 512) {
        int row = i >> 2, c8 = i & 3;
        v8h vv = {};
        if (row < LL) vv = *(const v8h*)(kg + (size_t)i * 8);
        *(v8h*)(Ks + row * 32 + ((c8 ^ (row & 3)) << 3)) = vv;
    }
    // V^T staging: [ktp][ch][key32], key-block XOR by (ch>>3)&3
    for (int i = tid; i < LP * 4; i += 512) {
        int key = i >> 2, c8 = i & 3;
        v8h vv = {};
        if (key < LL) vv = *(const v8h*)(vg + (size_t)key * HEADD + c8 * 8);
        int kk = key & 31;
        f16* d = Vts + (key >> 5) * 1024 + ((((kk >> 3) ^ c8) & 3) << 3) + (kk & 7);
#pragma unroll
        for (int j = 0; j < 8; ++j) d[(c8 * 8 + j) * 32] = vv[j];
    }
    __syncthreads();
    const float* bh = biasT + (size_t)h * LP * LP;     // [88 key-quads][352 q][4]
    const unsigned int* mg = mtb + (size_t)n * LP * MW;
    const v8h ones = {(f16)1.f, (f16)1.f, (f16)1.f, (f16)1.f,
                      (f16)1.f, (f16)1.f, (f16)1.f, (f16)1.f};
    const int kswz = (quad ^ (l15 & 3)) << 3;
    const int xw = (l15 >> 3) & 1;
    for (int qt = wave; qt < QT; qt += 8) {
        const int q = qt * 16 + l15;
        v8h af = *(const v8h*)(qg + (size_t)q * HEADD + quad * 8);      // Q[q][ch]
        uint4 mA = *(const uint4*)(mg + q * MW);
        uint4 mB = *(const uint4*)(mg + q * MW + 4);
        uint4 mC = *(const uint4*)(mg + q * MW + 8);
        unsigned int m[12] = {mA.x, mA.y, mA.z, mA.w, mB.x, mB.y, mB.z, mB.w,
                              mC.x, mC.y, mC.z, mC.w};
        const float* bq = bh + (size_t)q * 4;
        v4f cinN[2];
        cinN[0] = *(const v4f*)(bq + (size_t)(quad) * (LP * 4));
        cinN[1] = *(const v4f*)(bq + (size_t)(4 + quad) * (LP * 4));
        v4f o0 = {}, o1 = {}, o2 = {};
#pragma unroll
        for (int ktp = 0; ktp < 11; ++ktp) {
            v4f cin0 = cinN[0], cin1 = cinN[1];
            if (ktp < 10) {   // depth-1 prefetch: overlaps this tile's exp/PV
                cinN[0] = *(const v4f*)(bq + (size_t)((ktp + 1) * 8 + quad) * (LP * 4));
                cinN[1] = *(const v4f*)(bq + (size_t)((ktp + 1) * 8 + 4 + quad) * (LP * 4));
            }
            v8h bf0 = *(const v8h*)(Ks + (ktp * 32 + l15) * 32 + kswz);
            v8h bf1 = *(const v8h*)(Ks + (ktp * 32 + 16 + l15) * 32 + kswz);
            unsigned int mw = m[ktp];
            unsigned int mb0 = mw >> (quad * 4);
            unsigned int mb1 = mw >> (quad * 4 + 16);
#pragma unroll
            for (int e = 0; e < 4; ++e) {
                if ((mb0 >> e) & 1u) cin0[e] = NEGBIG_;
                if ((mb1 >> e) & 1u) cin1[e] = NEGBIG_;
            }
            // S^T tile: rows = keys (quad*4+e), cols = queries (l15)
            v4f s0 = __builtin_amdgcn_mfma_f32_16x16x32_f16(bf0, af, cin0, 0, 0, 0);
            v4f s1 = __builtin_amdgcn_mfma_f32_16x16x32_f16(bf1, af, cin1, 0, 0, 0);
            // x0: keys 4q+{0,1}; x1: 4q+{2,3}; y0: 16+4q+{0,1}; y1: 16+4q+{2,3} (query l15)
            unsigned int x0 = pk2(__builtin_amdgcn_exp2f(s0[0]), __builtin_amdgcn_exp2f(s0[1]));
            unsigned int x1 = pk2(__builtin_amdgcn_exp2f(s0[2]), __builtin_amdgcn_exp2f(s0[3]));
            unsigned int y0 = pk2(__builtin_amdgcn_exp2f(s1[0]), __builtin_amdgcn_exp2f(s1[1]));
            unsigned int y1 = pk2(__builtin_amdgcn_exp2f(s1[2]), __builtin_amdgcn_exp2f(s1[3]));
            // in-register redistribution: quad r ends with P[q=l15][keys 8r..8r+7]
            // swap32: vdst.hi32 <-> vsrc.lo32; swap16: per-half vdst.hi16 <-> vsrc.lo16
            v2u r0 = __builtin_amdgcn_permlane32_swap(x0, y0, false, false);
            v2u r1 = __builtin_amdgcn_permlane16_swap(r0[0], r0[1], false, false);
            v2u r2 = __builtin_amdgcn_permlane32_swap(x1, y1, false, false);
            v2u r3 = __builtin_amdgcn_permlane16_swap(r2[0], r2[1], false, false);
            uint4 av = make_uint4(r1[0], r3[0], r1[1], r3[1]);  // keys {0,1},{2,3},{4,5},{6,7} (+8*quad)
            v8h a = __builtin_bit_cast(v8h, av);
            const f16* vt = Vts + ktp * 1024;
            v8h w0 = *(const v8h*)(vt + l15 * 32 + ((quad ^ xw) << 3));            // ch 0..15
            v8h w1 = *(const v8h*)(vt + (16 + l15) * 32 + ((quad ^ 2 ^ xw) << 3)); // ch 16..31
            // O^T: rows = ch (quad*4+e), cols = queries (l15)
            o0 = __builtin_amdgcn_mfma_f32_16x16x32_f16(w0, a, o0, 0, 0, 0);
            o1 = __builtin_amdgcn_mfma_f32_16x16x32_f16(w1, a, o1, 0, 0, 0);
            o2 = __builtin_amdgcn_mfma_f32_16x16x32_f16(ones, a, o2, 0, 0, 0);  // rsum[q]
        }
        if (q < LL) {
            float inv = 1.0f / o2[0];          // rsum for this lane's query, uniform in e
            f16* orow = ao + ((size_t)(n * LL + q)) * DIMD + h * HEADD + quad * 4;
            v4h w0, w1;
#pragma unroll
            for (int e = 0; e < 4; ++e) {
                w0[e] = (f16)(o0[e] * inv);
                w1[e] = (f16)(o1[e] * inv);
            }
            *(v4h*)(orow) = w0;
            *(v4h*)(orow + 16) = w1;
        }
    }
}

// ---------------- proj GEMM (128x128, 2-phase dbuf pipeline, XCD swizzle) ----------------
__global__ __launch_bounds__(256) void proj_gemm(
    const f16* __restrict__ ao, const f16* __restrict__ pwt,
    const float* __restrict__ pb, float* __restrict__ out) {
    __shared__ f16 ABs[16384];
    const int lin = blockIdx.x;
    const int m0 = ((lin / 24) * 8 + (lin & 7)) * 128;
    const int n0 = ((lin >> 3) % 3) * 128;
    const int tid = threadIdx.x;
    const int wave = tid >> 6, lane = tid & 63;
    const int quad = lane >> 4, l15 = lane & 15;
    const int wm = (wave >> 1) * 64, wn = (wave & 1) * 64;
    const int srow = lane >> 2, scol = (lane & 3) * 8;
    const f16* ga0 = ao + (size_t)(m0 + wave * 32 + srow) * DIMD + scol;
    const f16* ga1 = ga0 + (size_t)16 * DIMD;
    const f16* gb0 = pwt + (size_t)(n0 + wave * 32 + srow) * DIMD + scol;
    const f16* gb1 = gb0 + (size_t)16 * DIMD;
    {
        f16* la = ABs + wave * 1024;
        async_cp16(ga0, la);
        async_cp16(ga1, la + 512);
        async_cp16(gb0, la + 4096);
        async_cp16(gb1, la + 4096 + 512);
    }
    __syncthreads();
    v4f acc[4][4] = {};
    for (int t = 0; t < 12; ++t) {
        const int cur = (t & 1) << 13;
        if (t < 11) {
            const int nk = (t + 1) * 32;
            f16* la = ABs + (cur ^ 8192) + wave * 1024;
            async_cp16(ga0 + nk, la);
            async_cp16(ga1 + nk, la + 512);
            async_cp16(gb0 + nk, la + 4096);
            async_cp16(gb1 + nk, la + 4096 + 512);
        }
        const f16* As = ABs + cur;
        const f16* Bs = As + 4096;
        v8h a[4], b[4];
#pragma unroll
        for (int i = 0; i < 4; ++i) a[i] = *(const v8h*)(As + (wm + i * 16 + l15) * 32 + quad * 8);
#pragma unroll
        for (int j = 0; j < 4; ++j) b[j] = *(const v8h*)(Bs + (wn + j * 16 + l15) * 32 + quad * 8);
#pragma unroll
        for (int i = 0; i < 4; ++i)
#pragma unroll
            for (int j = 0; j < 4; ++j)
                acc[i][j] = __builtin_amdgcn_mfma_f32_16x16x32_f16(a[i], b[j], acc[i][j], 0, 0, 0);
        __syncthreads();
    }
#pragma unroll
    for (int i = 0; i < 4; ++i)
#pragma unroll
        for (int e = 0; e < 4; ++e) {
            int gm = m0 + wm + i * 16 + quad * 4 + e;
            if (gm < NTOK) {
#pragma unroll
                for (int j = 0; j < 4; ++j) {
                    int gn = n0 + wn + j * 16 + l15;
                    out[(size_t)gm * DIMD + gn] = acc[i][j][e] + pb[gn];
                }
            }
        }
}

extern "C" void kernel_launch(void* const* d_in, const int* in_sizes, int n_in,
                              void* d_out, int out_size, void* d_ws, size_t ws_size,
                              hipStream_t stream) {
    const float* x      = (const float*)d_in[0];
    const float* qkv_w  = (const float*)d_in[1];
    const float* table  = (const float*)d_in[2];
    const float* proj_w = (const float*)d_in[3];
    const float* proj_b = (const float*)d_in[4];
    const int* mask     = (const int*)d_in[5];
    const int* rel      = (const int*)d_in[6];
    float* out = (float*)d_out;
    char* ws = (char*)d_ws;

    f16* q    = (f16*)(ws + OFF_Q);
    f16* k    = (f16*)(ws + OFF_K);
    f16* v    = (f16*)(ws + OFF_V);
    f16* xh   = (f16*)(ws + OFF_AO);   // xh and ao share the [MP][384] buffer
    f16* ao   = (f16*)(ws + OFF_AO);
    float* bt = (float*)(ws + OFF_BT);
    f16* wt   = (f16*)(ws + OFF_WT);
    f16* pwt  = (f16*)(ws + OFF_PWT);
    unsigned int* mtb = (unsigned int*)(ws + OFF_MTB);

    (void)hipFuncSetAttribute((const void*)attn_kernel,
                              hipFuncAttributeMaxDynamicSharedMemorySize, SMEM_ATTN);

    prep_all<<<(SPREP + 255) / 256, 256, 0, stream>>>(
        x, xh, qkv_w, wt, proj_w, pwt, table, rel, bt, mask, mtb);
    qkv_gemm<<<dim3(MPT * 9), 256, 0, stream>>>(xh, wt, q, k, v);
    attn_kernel<<<dim3(NWW * NHH), 512, SMEM_ATTN, stream>>>(q, k, v, bt, mtb, ao);
    proj_gemm<<<dim3(MPT * 3), 256, 0, stream>>>(ao, pwt, proj_b, out);
}

// Round 6
// 308.663 us; speedup vs baseline: 1.2879x; 1.2879x over previous
//
#include <hip/hip_runtime.h>

// WindowAttention (Swin-3D) on MI355X / gfx950.
// R19 = R18 with attn __launch_bounds__(512,6) -> (512,4). Theory: the
// permlane attn body needs ~90 VGPRs; the 6-wave bound capped it at 85 and
// forced scratch spill (250 MB writes + L2 thrash -> 368 MB bias re-fetch).
// 4-wave bound gives 128-reg budget, no spill. Everything else identical.

#define DIMD 384
#define NHH 12
#define HEADD 32
#define LL 343
#define NWW 64
#define NTOK (NWW * LL)            // 21952
#define MPT 176                    // m tiles (128 each)
#define MP (MPT * 128)             // 22528
#define LP 352                     // L padded to 22*16
#define QT 22
#define MW 12                      // mask words per query row (11 used)
#define SCALE_ 0.17677669529663687f
#define LOG2E_ 1.4426950408889634f
#define NEGBIG_ (-1.0e4f)

typedef _Float16 f16;
typedef _Float16 v8h __attribute__((ext_vector_type(8)));
typedef _Float16 v4h __attribute__((ext_vector_type(4)));
typedef float v4f __attribute__((ext_vector_type(4)));
typedef unsigned int v2u __attribute__((ext_vector_type(2)));

__device__ __forceinline__ void async_cp16(const void* g, void* l) {
    __builtin_amdgcn_global_load_lds(
        (const __attribute__((address_space(1))) void*)g,
        (__attribute__((address_space(3))) void*)l, 16, 0, 0);
}

__device__ __forceinline__ unsigned int pk2(float a, float b) {
    return __builtin_bit_cast(unsigned int, __builtin_amdgcn_cvt_pkrtz(a, b));
}

// ---- workspace layout (bytes) ----
constexpr size_t HBUF = (size_t)NHH * MP * HEADD * 2;          // per q/k/v
constexpr size_t OFF_Q    = 0;
constexpr size_t OFF_K    = OFF_Q  + HBUF;
constexpr size_t OFF_V    = OFF_K  + HBUF;
constexpr size_t OFF_AO   = OFF_V  + HBUF;                     // f16 [MP][384]; xh then AO
constexpr size_t OFF_BT   = OFF_AO + (size_t)MP * DIMD * 2;    // f32 biasT (NH,88,352,4) *log2e, key-major
constexpr size_t OFF_WT   = OFF_BT + (size_t)NHH * LP * LP * 4;
constexpr size_t OFF_PWT  = OFF_WT + (size_t)3 * DIMD * DIMD * 2;
constexpr size_t OFF_MTB  = OFF_PWT + (size_t)DIMD * DIMD * 2; // uint (NW, 352 queries, 12 key-words)

// attn LDS: Ks [352][32] + Vts [11][32][32]
constexpr int SMEM_ATTN = (LP * 32 + LP * 32) * 2;   // 45056

// ---------------- fused prep ----------------
#define S0 (NTOK * DIMD / 4)
#define S1 (3 * DIMD * DIMD)
#define S2 (DIMD * DIMD)
#define S3 (NHH * LP * LP)
#define S4 (NWW * MW * LP)
#define SPREP (S0 + S1 + S2 + S3 + S4)

__global__ __launch_bounds__(256) void prep_all(
    const float* __restrict__ x, f16* __restrict__ xh,
    const float* __restrict__ qkv_w, f16* __restrict__ wt,
    const float* __restrict__ proj_w, f16* __restrict__ pwt,
    const float* __restrict__ table, const int* __restrict__ rel, float* __restrict__ btf,
    const int* __restrict__ mask, unsigned int* __restrict__ mtb) {
    int t = blockIdx.x * 256 + threadIdx.x;
    if (t < S0) {
        float4 v = *(const float4*)(x + (size_t)t * 4);
        v4h o; o[0] = (f16)v.x; o[1] = (f16)v.y; o[2] = (f16)v.z; o[3] = (f16)v.w;
        *(v4h*)(xh + (size_t)t * 4) = o;
    } else if (t < S0 + S1) {
        int e = t - S0;
        int n = e / DIMD, k = e % DIMD;          // wt[n][k] = qkv_w[k][n]
        wt[e] = (f16)qkv_w[(size_t)k * (3 * DIMD) + n];
    } else if (t < S0 + S1 + S2) {
        int e = t - S0 - S1;
        int n = e / DIMD, k = e % DIMD;
        pwt[e] = (f16)proj_w[(size_t)k * DIMD + n];
    } else if (t < S0 + S1 + S2 + S3) {
        // biasT[h][kq][q][e2] = bias(h, query=q, key=kq*4+e2)*log2e, pads -> -1e4
        int e = t - S0 - S1 - S2;
        int h = e / (LP * LP), rem = e % (LP * LP);
        int kq = rem / (LP * 4);
        int rem2 = rem % (LP * 4);
        int col = rem2 >> 2, e2 = rem2 & 3;      // col = query
        int key = kq * 4 + e2;
        float v = NEGBIG_;
        if (col < LL && key < LL) v = table[(size_t)rel[col * LL + key] * NHH + h] * LOG2E_;
        btf[e] = v;
    } else if (t < SPREP) {
        // mtb[n][q][kw]: bit b = mask[n][query q][key kw*32+b]
        int e = t - S0 - S1 - S2 - S3;
        int n = e / (MW * LP), rem = e % (MW * LP);
        int q = rem / MW, kw = rem % MW;
        unsigned int wd = 0;
        if (q < LL && kw < 11) {
            int kbase = kw * 32;
            int kmax = LL - kbase; if (kmax > 32) kmax = 32;
            const int* mrow = mask + ((size_t)n * LL + q) * LL + kbase;
#pragma unroll 4
            for (int b = 0; b < kmax; ++b)
                if (mrow[b]) wd |= (1u << b);
        }
        mtb[((size_t)n * LP + q) * MW + kw] = wd;
    }
}

// ---------------- QKV GEMM (128x128, 2-phase dbuf pipeline, XCD swizzle) ----------------
__global__ __launch_bounds__(256) void qkv_gemm(
    const f16* __restrict__ xh, const f16* __restrict__ wt,
    f16* __restrict__ qb, f16* __restrict__ kb, f16* __restrict__ vb) {
    __shared__ f16 ABs[16384];       // 2 bufs x (A 128x32 + B 128x32)
    const int lin = blockIdx.x;
    const int m0 = ((lin / 72) * 8 + (lin & 7)) * 128;
    const int n0 = ((lin >> 3) % 9) * 128;
    const int tid = threadIdx.x;
    const int wave = tid >> 6, lane = tid & 63;
    const int quad = lane >> 4, l15 = lane & 15;
    const int wm = (wave >> 1) * 64, wn = (wave & 1) * 64;
    const int srow = lane >> 2, scol = (lane & 3) * 8;
    const f16* ga0 = xh + (size_t)(m0 + wave * 32 + srow) * DIMD + scol;
    const f16* ga1 = ga0 + (size_t)16 * DIMD;
    const f16* gb0 = wt + (size_t)(n0 + wave * 32 + srow) * DIMD + scol;
    const f16* gb1 = gb0 + (size_t)16 * DIMD;
    {
        f16* la = ABs + wave * 1024;
        async_cp16(ga0, la);
        async_cp16(ga1, la + 512);
        async_cp16(gb0, la + 4096);
        async_cp16(gb1, la + 4096 + 512);
    }
    __syncthreads();
    v4f acc[4][4] = {};
    for (int t = 0; t < 12; ++t) {
        const int cur = (t & 1) << 13;          // 0 / 8192 f16 flip
        if (t < 11) {                            // prefetch next tile: overlaps MFMA below
            const int nk = (t + 1) * 32;
            f16* la = ABs + (cur ^ 8192) + wave * 1024;
            async_cp16(ga0 + nk, la);
            async_cp16(ga1 + nk, la + 512);
            async_cp16(gb0 + nk, la + 4096);
            async_cp16(gb1 + nk, la + 4096 + 512);
        }
        const f16* As = ABs + cur;
        const f16* Bs = As + 4096;
        v8h a[4], b[4];
#pragma unroll
        for (int i = 0; i < 4; ++i) a[i] = *(const v8h*)(As + (wm + i * 16 + l15) * 32 + quad * 8);
#pragma unroll
        for (int j = 0; j < 4; ++j) b[j] = *(const v8h*)(Bs + (wn + j * 16 + l15) * 32 + quad * 8);
#pragma unroll
        for (int i = 0; i < 4; ++i)
#pragma unroll
            for (int j = 0; j < 4; ++j)
                acc[i][j] = __builtin_amdgcn_mfma_f32_16x16x32_f16(a[i], b[j], acc[i][j], 0, 0, 0);
        __syncthreads();                         // single barrier: drains prefetch (vmcnt0) + protects buf reuse
    }
    // epilogue: per-wave private LDS transpose, zero barriers, coalesced 16B stores
    const int t3 = n0 / DIMD;
    f16* dst = (t3 == 0) ? qb : (t3 == 1) ? kb : vb;
    const float sc = (t3 == 0) ? (SCALE_ * LOG2E_) : 1.0f;
    const int nrel = n0 - t3 * DIMD;
    f16* Cw = ABs + wave * (16 * 72);            // [16 rows][72 stride], wave-private
#pragma unroll
    for (int i = 0; i < 4; ++i) {
#pragma unroll
        for (int e = 0; e < 4; ++e)
#pragma unroll
            for (int j = 0; j < 4; ++j)
                Cw[(quad * 4 + e) * 72 + j * 16 + l15] = (f16)(acc[i][j][e] * sc);
        // same-wave DS ordering: no barrier needed
#pragma unroll
        for (int c = 0; c < 2; ++c) {
            int chunk = quad + c * 4;            // 0..7 -> 8-col piece
            int gm = m0 + wm + i * 16 + l15;
            int gcol = nrel + wn + chunk * 8;
            if (gm < NTOK) {
                size_t off = (size_t)(gcol >> 5) * ((size_t)MP * HEADD)
                           + (gcol & 31) + (size_t)gm * HEADD;
                *(v8h*)(dst + off) = *(const v8h*)(Cw + l15 * 72 + chunk * 8);
            }
        }
    }
}

// ---------------- attention (S^T tiles, reg-mask, permlane P, 4-wave bound) ----------------
__global__ __launch_bounds__(512, 4) void attn_kernel(
    const f16* __restrict__ qb, const f16* __restrict__ kb, const f16* __restrict__ vb,
    const float* __restrict__ biasT, const unsigned int* __restrict__ mtb,
    f16* __restrict__ ao) {
    extern __shared__ char smem[];
    f16* Ks  = (f16*)smem;            // [352 keys][32 ch], 16B-block XOR by (key&3)
    f16* Vts = Ks + LP * 32;          // [11 ktp][32 ch][32 keys], key-block XOR by (ch>>3)&3
    const int bid = blockIdx.x;
    // XCD-chunked swizzle: XCD x owns j2 in [96x, 96x+96) -> 1.5 head slices per XCD L2
    const int j2 = (bid & 7) * 96 + (bid >> 3);
    const int n = j2 & 63, h = j2 >> 6;
    const int tid = threadIdx.x, wave = tid >> 6, lane = tid & 63;
    const int quad = lane >> 4, l15 = lane & 15;
    const size_t slice = ((size_t)h * MP + n * LL) * HEADD;
    const f16* qg = qb + slice;
    const f16* kg = kb + slice;
    const f16* vg = vb + slice;
    // K staging: [key][32ch], swizzled 16B blocks, zero-pad keys >= LL
    for (int i = tid; i < LP * 4; i += 512) {
        int row = i >> 2, c8 = i & 3;
        v8h vv = {};
        if (row < LL) vv = *(const v8h*)(kg + (size_t)i * 8);
        *(v8h*)(Ks + row * 32 + ((c8 ^ (row & 3)) << 3)) = vv;
    }
    // V^T staging: [ktp][ch][key32], key-block XOR by (ch>>3)&3
    for (int i = tid; i < LP * 4; i += 512) {
        int key = i >> 2, c8 = i & 3;
        v8h vv = {};
        if (key < LL) vv = *(const v8h*)(vg + (size_t)key * HEADD + c8 * 8);
        int kk = key & 31;
        f16* d = Vts + (key >> 5) * 1024 + ((((kk >> 3) ^ c8) & 3) << 3) + (kk & 7);
#pragma unroll
        for (int j = 0; j < 8; ++j) d[(c8 * 8 + j) * 32] = vv[j];
    }
    __syncthreads();
    const float* bh = biasT + (size_t)h * LP * LP;     // [88 key-quads][352 q][4]
    const unsigned int* mg = mtb + (size_t)n * LP * MW;
    const v8h ones = {(f16)1.f, (f16)1.f, (f16)1.f, (f16)1.f,
                      (f16)1.f, (f16)1.f, (f16)1.f, (f16)1.f};
    const int kswz = (quad ^ (l15 & 3)) << 3;
    const int xw = (l15 >> 3) & 1;
    for (int qt = wave; qt < QT; qt += 8) {
        const int q = qt * 16 + l15;
        v8h af = *(const v8h*)(qg + (size_t)q * HEADD + quad * 8);      // Q[q][ch]
        uint4 mA = *(const uint4*)(mg + q * MW);
        uint4 mB = *(const uint4*)(mg + q * MW + 4);
        uint4 mC = *(const uint4*)(mg + q * MW + 8);
        unsigned int m[12] = {mA.x, mA.y, mA.z, mA.w, mB.x, mB.y, mB.z, mB.w,
                              mC.x, mC.y, mC.z, mC.w};
        const float* bq = bh + (size_t)q * 4;
        v4f cinN[2];
        cinN[0] = *(const v4f*)(bq + (size_t)(quad) * (LP * 4));
        cinN[1] = *(const v4f*)(bq + (size_t)(4 + quad) * (LP * 4));
        v4f o0 = {}, o1 = {}, o2 = {};
#pragma unroll
        for (int ktp = 0; ktp < 11; ++ktp) {
            v4f cin0 = cinN[0], cin1 = cinN[1];
            if (ktp < 10) {   // depth-1 prefetch: overlaps this tile's exp/PV
                cinN[0] = *(const v4f*)(bq + (size_t)((ktp + 1) * 8 + quad) * (LP * 4));
                cinN[1] = *(const v4f*)(bq + (size_t)((ktp + 1) * 8 + 4 + quad) * (LP * 4));
            }
            v8h bf0 = *(const v8h*)(Ks + (ktp * 32 + l15) * 32 + kswz);
            v8h bf1 = *(const v8h*)(Ks + (ktp * 32 + 16 + l15) * 32 + kswz);
            unsigned int mw = m[ktp];
            unsigned int mb0 = mw >> (quad * 4);
            unsigned int mb1 = mw >> (quad * 4 + 16);
#pragma unroll
            for (int e = 0; e < 4; ++e) {
                if ((mb0 >> e) & 1u) cin0[e] = NEGBIG_;
                if ((mb1 >> e) & 1u) cin1[e] = NEGBIG_;
            }
            // S^T tile: rows = keys (quad*4+e), cols = queries (l15)
            v4f s0 = __builtin_amdgcn_mfma_f32_16x16x32_f16(bf0, af, cin0, 0, 0, 0);
            v4f s1 = __builtin_amdgcn_mfma_f32_16x16x32_f16(bf1, af, cin1, 0, 0, 0);
            // x0: keys 4q+{0,1}; x1: 4q+{2,3}; y0: 16+4q+{0,1}; y1: 16+4q+{2,3} (query l15)
            unsigned int x0 = pk2(__builtin_amdgcn_exp2f(s0[0]), __builtin_amdgcn_exp2f(s0[1]));
            unsigned int x1 = pk2(__builtin_amdgcn_exp2f(s0[2]), __builtin_amdgcn_exp2f(s0[3]));
            unsigned int y0 = pk2(__builtin_amdgcn_exp2f(s1[0]), __builtin_amdgcn_exp2f(s1[1]));
            unsigned int y1 = pk2(__builtin_amdgcn_exp2f(s1[2]), __builtin_amdgcn_exp2f(s1[3]));
            // in-register redistribution: quad r ends with P[q=l15][keys 8r..8r+7]
            // swap32: vdst.hi32 <-> vsrc.lo32; swap16: per-half vdst.hi16 <-> vsrc.lo16
            v2u r0 = __builtin_amdgcn_permlane32_swap(x0, y0, false, false);
            v2u r1 = __builtin_amdgcn_permlane16_swap(r0[0], r0[1], false, false);
            v2u r2 = __builtin_amdgcn_permlane32_swap(x1, y1, false, false);
            v2u r3 = __builtin_amdgcn_permlane16_swap(r2[0], r2[1], false, false);
            uint4 av = make_uint4(r1[0], r3[0], r1[1], r3[1]);  // keys {0,1},{2,3},{4,5},{6,7} (+8*quad)
            v8h a = __builtin_bit_cast(v8h, av);
            const f16* vt = Vts + ktp * 1024;
            v8h w0 = *(const v8h*)(vt + l15 * 32 + ((quad ^ xw) << 3));            // ch 0..15
            v8h w1 = *(const v8h*)(vt + (16 + l15) * 32 + ((quad ^ 2 ^ xw) << 3)); // ch 16..31
            // O^T: rows = ch (quad*4+e), cols = queries (l15)
            o0 = __builtin_amdgcn_mfma_f32_16x16x32_f16(w0, a, o0, 0, 0, 0);
            o1 = __builtin_amdgcn_mfma_f32_16x16x32_f16(w1, a, o1, 0, 0, 0);
            o2 = __builtin_amdgcn_mfma_f32_16x16x32_f16(ones, a, o2, 0, 0, 0);  // rsum[q]
        }
        if (q < LL) {
            float inv = 1.0f / o2[0];          // rsum for this lane's query, uniform in e
            f16* orow = ao + ((size_t)(n * LL + q)) * DIMD + h * HEADD + quad * 4;
            v4h w0, w1;
#pragma unroll
            for (int e = 0; e < 4; ++e) {
                w0[e] = (f16)(o0[e] * inv);
                w1[e] = (f16)(o1[e] * inv);
            }
            *(v4h*)(orow) = w0;
            *(v4h*)(orow + 16) = w1;
        }
    }
}

// ---------------- proj GEMM (128x128, 2-phase dbuf pipeline, XCD swizzle) ----------------
__global__ __launch_bounds__(256) void proj_gemm(
    const f16* __restrict__ ao, const f16* __restrict__ pwt,
    const float* __restrict__ pb, float* __restrict__ out) {
    __shared__ f16 ABs[16384];
    const int lin = blockIdx.x;
    const int m0 = ((lin / 24) * 8 + (lin & 7)) * 128;
    const int n0 = ((lin >> 3) % 3) * 128;
    const int tid = threadIdx.x;
    const int wave = tid >> 6, lane = tid & 63;
    const int quad = lane >> 4, l15 = lane & 15;
    const int wm = (wave >> 1) * 64, wn = (wave & 1) * 64;
    const int srow = lane >> 2, scol = (lane & 3) * 8;
    const f16* ga0 = ao + (size_t)(m0 + wave * 32 + srow) * DIMD + scol;
    const f16* ga1 = ga0 + (size_t)16 * DIMD;
    const f16* gb0 = pwt + (size_t)(n0 + wave * 32 + srow) * DIMD + scol;
    const f16* gb1 = gb0 + (size_t)16 * DIMD;
    {
        f16* la = ABs + wave * 1024;
        async_cp16(ga0, la);
        async_cp16(ga1, la + 512);
        async_cp16(gb0, la + 4096);
        async_cp16(gb1, la + 4096 + 512);
    }
    __syncthreads();
    v4f acc[4][4] = {};
    for (int t = 0; t < 12; ++t) {
        const int cur = (t & 1) << 13;
        if (t < 11) {
            const int nk = (t + 1) * 32;
            f16* la = ABs + (cur ^ 8192) + wave * 1024;
            async_cp16(ga0 + nk, la);
            async_cp16(ga1 + nk, la + 512);
            async_cp16(gb0 + nk, la + 4096);
            async_cp16(gb1 + nk, la + 4096 + 512);
        }
        const f16* As = ABs + cur;
        const f16* Bs = As + 4096;
        v8h a[4], b[4];
#pragma unroll
        for (int i = 0; i < 4; ++i) a[i] = *(const v8h*)(As + (wm + i * 16 + l15) * 32 + quad * 8);
#pragma unroll
        for (int j = 0; j < 4; ++j) b[j] = *(const v8h*)(Bs + (wn + j * 16 + l15) * 32 + quad * 8);
#pragma unroll
        for (int i = 0; i < 4; ++i)
#pragma unroll
            for (int j = 0; j < 4; ++j)
                acc[i][j] = __builtin_amdgcn_mfma_f32_16x16x32_f16(a[i], b[j], acc[i][j], 0, 0, 0);
        __syncthreads();
    }
#pragma unroll
    for (int i = 0; i < 4; ++i)
#pragma unroll
        for (int e = 0; e < 4; ++e) {
            int gm = m0 + wm + i * 16 + quad * 4 + e;
            if (gm < NTOK) {
#pragma unroll
                for (int j = 0; j < 4; ++j) {
                    int gn = n0 + wn + j * 16 + l15;
                    out[(size_t)gm * DIMD + gn] = acc[i][j][e] + pb[gn];
                }
            }
        }
}

extern "C" void kernel_launch(void* const* d_in, const int* in_sizes, int n_in,
                              void* d_out, int out_size, void* d_ws, size_t ws_size,
                              hipStream_t stream) {
    const float* x      = (const float*)d_in[0];
    const float* qkv_w  = (const float*)d_in[1];
    const float* table  = (const float*)d_in[2];
    const float* proj_w = (const float*)d_in[3];
    const float* proj_b = (const float*)d_in[4];
    const int* mask     = (const int*)d_in[5];
    const int* rel      = (const int*)d_in[6];
    float* out = (float*)d_out;
    char* ws = (char*)d_ws;

    f16* q    = (f16*)(ws + OFF_Q);
    f16* k    = (f16*)(ws + OFF_K);
    f16* v    = (f16*)(ws + OFF_V);
    f16* xh   = (f16*)(ws + OFF_AO);   // xh and ao share the [MP][384] buffer
    f16* ao   = (f16*)(ws + OFF_AO);
    float* bt = (float*)(ws + OFF_BT);
    f16* wt   = (f16*)(ws + OFF_WT);
    f16* pwt  = (f16*)(ws + OFF_PWT);
    unsigned int* mtb = (unsigned int*)(ws + OFF_MTB);

    (void)hipFuncSetAttribute((const void*)attn_kernel,
                              hipFuncAttributeMaxDynamicSharedMemorySize, SMEM_ATTN);

    prep_all<<<(SPREP + 255) / 256, 256, 0, stream>>>(
        x, xh, qkv_w, wt, proj_w, pwt, table, rel, bt, mask, mtb);
    qkv_gemm<<<dim3(MPT * 9), 256, 0, stream>>>(xh, wt, q, k, v);
    attn_kernel<<<dim3(NWW * NHH), 512, SMEM_ATTN, stream>>>(q, k, v, bt, mtb, ao);
    proj_gemm<<<dim3(MPT * 3), 256, 0, stream>>>(ao, pwt, proj_b, out);
}

// Round 7
// 211.757 us; speedup vs baseline: 1.8772x; 1.4576x over previous
//
#include <hip/hip_runtime.h>

// WindowAttention (Swin-3D) on MI355X / gfx950.
// R21 = proven-parts recombination. attn: R15's LDS P round-trip (uint2
// b64 stores, bank-uniform; VGPR 40, zero scratch — measured) + R16's
// conflict-free Vts [ktp][32ch][32key] XOR layout (conflicts 6.35M->1.08M —
// measured, and results verified). The permlane path is abandoned: despite
// correctness it generated ~160MB/dispatch of scratch traffic regardless of
// launch bounds. GEMMs keep the R16 2-phase dbuf pipeline. LDS 53248 B.

#define DIMD 384
#define NHH 12
#define HEADD 32
#define LL 343
#define NWW 64
#define NTOK (NWW * LL)            // 21952
#define MPT 176                    // m tiles (128 each)
#define MP (MPT * 128)             // 22528
#define LP 352                     // L padded to 22*16
#define QT 22
#define MW 12                      // mask words per query row (11 used)
#define SCALE_ 0.17677669529663687f
#define LOG2E_ 1.4426950408889634f
#define NEGBIG_ (-1.0e4f)

typedef _Float16 f16;
typedef _Float16 v8h __attribute__((ext_vector_type(8)));
typedef _Float16 v4h __attribute__((ext_vector_type(4)));
typedef float v4f __attribute__((ext_vector_type(4)));

__device__ __forceinline__ void async_cp16(const void* g, void* l) {
    __builtin_amdgcn_global_load_lds(
        (const __attribute__((address_space(1))) void*)g,
        (__attribute__((address_space(3))) void*)l, 16, 0, 0);
}

__device__ __forceinline__ unsigned int pk2(float a, float b) {
    return __builtin_bit_cast(unsigned int, __builtin_amdgcn_cvt_pkrtz(a, b));
}

// ---- workspace layout (bytes) ----
constexpr size_t HBUF = (size_t)NHH * MP * HEADD * 2;          // per q/k/v
constexpr size_t OFF_Q    = 0;
constexpr size_t OFF_K    = OFF_Q  + HBUF;
constexpr size_t OFF_V    = OFF_K  + HBUF;
constexpr size_t OFF_AO   = OFF_V  + HBUF;                     // f16 [MP][384]; xh then AO
constexpr size_t OFF_BT   = OFF_AO + (size_t)MP * DIMD * 2;    // f32 biasT (NH,88,352,4) *log2e, key-major
constexpr size_t OFF_WT   = OFF_BT + (size_t)NHH * LP * LP * 4;
constexpr size_t OFF_PWT  = OFF_WT + (size_t)3 * DIMD * DIMD * 2;
constexpr size_t OFF_MTB  = OFF_PWT + (size_t)DIMD * DIMD * 2; // uint (NW, 352 queries, 12 key-words)

// attn LDS: Ks [352][32] + Vts [11][32][32] + Ps 8x[16][32]
constexpr int SMEM_ATTN = (LP * 32 + LP * 32 + 8 * 16 * 32) * 2;   // 53248

// ---------------- fused prep ----------------
#define S0 (NTOK * DIMD / 4)
#define S1 (3 * DIMD * DIMD)
#define S2 (DIMD * DIMD)
#define S3 (NHH * LP * LP)
#define S4 (NWW * MW * LP)
#define SPREP (S0 + S1 + S2 + S3 + S4)

__global__ __launch_bounds__(256) void prep_all(
    const float* __restrict__ x, f16* __restrict__ xh,
    const float* __restrict__ qkv_w, f16* __restrict__ wt,
    const float* __restrict__ proj_w, f16* __restrict__ pwt,
    const float* __restrict__ table, const int* __restrict__ rel, float* __restrict__ btf,
    const int* __restrict__ mask, unsigned int* __restrict__ mtb) {
    int t = blockIdx.x * 256 + threadIdx.x;
    if (t < S0) {
        float4 v = *(const float4*)(x + (size_t)t * 4);
        v4h o; o[0] = (f16)v.x; o[1] = (f16)v.y; o[2] = (f16)v.z; o[3] = (f16)v.w;
        *(v4h*)(xh + (size_t)t * 4) = o;
    } else if (t < S0 + S1) {
        int e = t - S0;
        int n = e / DIMD, k = e % DIMD;          // wt[n][k] = qkv_w[k][n]
        wt[e] = (f16)qkv_w[(size_t)k * (3 * DIMD) + n];
    } else if (t < S0 + S1 + S2) {
        int e = t - S0 - S1;
        int n = e / DIMD, k = e % DIMD;
        pwt[e] = (f16)proj_w[(size_t)k * DIMD + n];
    } else if (t < S0 + S1 + S2 + S3) {
        // biasT[h][kq][q][e2] = bias(h, query=q, key=kq*4+e2)*log2e, pads -> -1e4
        int e = t - S0 - S1 - S2;
        int h = e / (LP * LP), rem = e % (LP * LP);
        int kq = rem / (LP * 4);
        int rem2 = rem % (LP * 4);
        int col = rem2 >> 2, e2 = rem2 & 3;      // col = query
        int key = kq * 4 + e2;
        float v = NEGBIG_;
        if (col < LL && key < LL) v = table[(size_t)rel[col * LL + key] * NHH + h] * LOG2E_;
        btf[e] = v;
    } else if (t < SPREP) {
        // mtb[n][q][kw]: bit b = mask[n][query q][key kw*32+b]
        int e = t - S0 - S1 - S2 - S3;
        int n = e / (MW * LP), rem = e % (MW * LP);
        int q = rem / MW, kw = rem % MW;
        unsigned int wd = 0;
        if (q < LL && kw < 11) {
            int kbase = kw * 32;
            int kmax = LL - kbase; if (kmax > 32) kmax = 32;
            const int* mrow = mask + ((size_t)n * LL + q) * LL + kbase;
#pragma unroll 4
            for (int b = 0; b < kmax; ++b)
                if (mrow[b]) wd |= (1u << b);
        }
        mtb[((size_t)n * LP + q) * MW + kw] = wd;
    }
}

// ---------------- QKV GEMM (128x128, 2-phase dbuf pipeline, XCD swizzle) ----------------
__global__ __launch_bounds__(256) void qkv_gemm(
    const f16* __restrict__ xh, const f16* __restrict__ wt,
    f16* __restrict__ qb, f16* __restrict__ kb, f16* __restrict__ vb) {
    __shared__ f16 ABs[16384];       // 2 bufs x (A 128x32 + B 128x32)
    const int lin = blockIdx.x;
    const int m0 = ((lin / 72) * 8 + (lin & 7)) * 128;
    const int n0 = ((lin >> 3) % 9) * 128;
    const int tid = threadIdx.x;
    const int wave = tid >> 6, lane = tid & 63;
    const int quad = lane >> 4, l15 = lane & 15;
    const int wm = (wave >> 1) * 64, wn = (wave & 1) * 64;
    const int srow = lane >> 2, scol = (lane & 3) * 8;
    const f16* ga0 = xh + (size_t)(m0 + wave * 32 + srow) * DIMD + scol;
    const f16* ga1 = ga0 + (size_t)16 * DIMD;
    const f16* gb0 = wt + (size_t)(n0 + wave * 32 + srow) * DIMD + scol;
    const f16* gb1 = gb0 + (size_t)16 * DIMD;
    {
        f16* la = ABs + wave * 1024;
        async_cp16(ga0, la);
        async_cp16(ga1, la + 512);
        async_cp16(gb0, la + 4096);
        async_cp16(gb1, la + 4096 + 512);
    }
    __syncthreads();
    v4f acc[4][4] = {};
    for (int t = 0; t < 12; ++t) {
        const int cur = (t & 1) << 13;          // 0 / 8192 f16 flip
        if (t < 11) {                            // prefetch next tile: overlaps MFMA below
            const int nk = (t + 1) * 32;
            f16* la = ABs + (cur ^ 8192) + wave * 1024;
            async_cp16(ga0 + nk, la);
            async_cp16(ga1 + nk, la + 512);
            async_cp16(gb0 + nk, la + 4096);
            async_cp16(gb1 + nk, la + 4096 + 512);
        }
        const f16* As = ABs + cur;
        const f16* Bs = As + 4096;
        v8h a[4], b[4];
#pragma unroll
        for (int i = 0; i < 4; ++i) a[i] = *(const v8h*)(As + (wm + i * 16 + l15) * 32 + quad * 8);
#pragma unroll
        for (int j = 0; j < 4; ++j) b[j] = *(const v8h*)(Bs + (wn + j * 16 + l15) * 32 + quad * 8);
#pragma unroll
        for (int i = 0; i < 4; ++i)
#pragma unroll
            for (int j = 0; j < 4; ++j)
                acc[i][j] = __builtin_amdgcn_mfma_f32_16x16x32_f16(a[i], b[j], acc[i][j], 0, 0, 0);
        __syncthreads();                         // single barrier: drains prefetch (vmcnt0) + protects buf reuse
    }
    // epilogue: per-wave private LDS transpose, zero barriers, coalesced 16B stores
    const int t3 = n0 / DIMD;
    f16* dst = (t3 == 0) ? qb : (t3 == 1) ? kb : vb;
    const float sc = (t3 == 0) ? (SCALE_ * LOG2E_) : 1.0f;
    const int nrel = n0 - t3 * DIMD;
    f16* Cw = ABs + wave * (16 * 72);            // [16 rows][72 stride], wave-private
#pragma unroll
    for (int i = 0; i < 4; ++i) {
#pragma unroll
        for (int e = 0; e < 4; ++e)
#pragma unroll
            for (int j = 0; j < 4; ++j)
                Cw[(quad * 4 + e) * 72 + j * 16 + l15] = (f16)(acc[i][j][e] * sc);
        // same-wave DS ordering: no barrier needed
#pragma unroll
        for (int c = 0; c < 2; ++c) {
            int chunk = quad + c * 4;            // 0..7 -> 8-col piece
            int gm = m0 + wm + i * 16 + l15;
            int gcol = nrel + wn + chunk * 8;
            if (gm < NTOK) {
                size_t off = (size_t)(gcol >> 5) * ((size_t)MP * HEADD)
                           + (gcol & 31) + (size_t)gm * HEADD;
                *(v8h*)(dst + off) = *(const v8h*)(Cw + l15 * 72 + chunk * 8);
            }
        }
    }
}

// ---------------- attention (S^T tiles, reg-mask, LDS-P, new Vts, 3 blk/CU) ----------------
__global__ __launch_bounds__(512, 6) void attn_kernel(
    const f16* __restrict__ qb, const f16* __restrict__ kb, const f16* __restrict__ vb,
    const float* __restrict__ biasT, const unsigned int* __restrict__ mtb,
    f16* __restrict__ ao) {
    extern __shared__ char smem[];
    f16* Ks  = (f16*)smem;            // [352 keys][32 ch], 16B-block XOR by (key&3)
    f16* Vts = Ks + LP * 32;          // [11 ktp][32 ch][32 keys], key-block XOR by (ch>>3)&3
    f16* Ps  = Vts + LP * 32;         // 8 waves x [16 q][32 keys], block XOR by ((l15>>1)&3)
    const int bid = blockIdx.x;
    // XCD-chunked swizzle: XCD x owns j2 in [96x, 96x+96) -> 1.5 head slices per XCD L2
    const int j2 = (bid & 7) * 96 + (bid >> 3);
    const int n = j2 & 63, h = j2 >> 6;
    const int tid = threadIdx.x, wave = tid >> 6, lane = tid & 63;
    const int quad = lane >> 4, l15 = lane & 15;
    const size_t slice = ((size_t)h * MP + n * LL) * HEADD;
    const f16* qg = qb + slice;
    const f16* kg = kb + slice;
    const f16* vg = vb + slice;
    // K staging: [key][32ch], swizzled 16B blocks, zero-pad keys >= LL
    for (int i = tid; i < LP * 4; i += 512) {
        int row = i >> 2, c8 = i & 3;
        v8h vv = {};
        if (row < LL) vv = *(const v8h*)(kg + (size_t)i * 8);
        *(v8h*)(Ks + row * 32 + ((c8 ^ (row & 3)) << 3)) = vv;
    }
    // V^T staging: [ktp][ch][key32], key-block XOR by (ch>>3)&3
    for (int i = tid; i < LP * 4; i += 512) {
        int key = i >> 2, c8 = i & 3;
        v8h vv = {};
        if (key < LL) vv = *(const v8h*)(vg + (size_t)key * HEADD + c8 * 8);
        int kk = key & 31;
        f16* d = Vts + (key >> 5) * 1024 + ((((kk >> 3) ^ c8) & 3) << 3) + (kk & 7);
#pragma unroll
        for (int j = 0; j < 8; ++j) d[(c8 * 8 + j) * 32] = vv[j];
    }
    __syncthreads();
    f16* Pw = Ps + wave * (16 * 32);
    const float* bh = biasT + (size_t)h * LP * LP;     // [88 key-quads][352 q][4]
    const unsigned int* mg = mtb + (size_t)n * LP * MW;
    const v8h ones = {(f16)1.f, (f16)1.f, (f16)1.f, (f16)1.f,
                      (f16)1.f, (f16)1.f, (f16)1.f, (f16)1.f};
    const int pswz = (l15 >> 1) & 3;
    const int kswz = (quad ^ (l15 & 3)) << 3;
    const int xw = (l15 >> 3) & 1;
    for (int qt = wave; qt < QT; qt += 8) {
        const int q = qt * 16 + l15;
        v8h af = *(const v8h*)(qg + (size_t)q * HEADD + quad * 8);      // Q[q][ch]
        uint4 mA = *(const uint4*)(mg + q * MW);
        uint4 mB = *(const uint4*)(mg + q * MW + 4);
        uint4 mC = *(const uint4*)(mg + q * MW + 8);
        unsigned int m[12] = {mA.x, mA.y, mA.z, mA.w, mB.x, mB.y, mB.z, mB.w,
                              mC.x, mC.y, mC.z, mC.w};
        const float* bq = bh + (size_t)q * 4;
        v4f cinN[2];
        cinN[0] = *(const v4f*)(bq + (size_t)(quad) * (LP * 4));
        cinN[1] = *(const v4f*)(bq + (size_t)(4 + quad) * (LP * 4));
        v4f o0 = {}, o1 = {}, o2 = {};
#pragma unroll
        for (int ktp = 0; ktp < 11; ++ktp) {
            v4f cin0 = cinN[0], cin1 = cinN[1];
            if (ktp < 10) {   // depth-1 prefetch: overlaps this tile's exp/PV
                cinN[0] = *(const v4f*)(bq + (size_t)((ktp + 1) * 8 + quad) * (LP * 4));
                cinN[1] = *(const v4f*)(bq + (size_t)((ktp + 1) * 8 + 4 + quad) * (LP * 4));
            }
            v8h bf0 = *(const v8h*)(Ks + (ktp * 32 + l15) * 32 + kswz);
            v8h bf1 = *(const v8h*)(Ks + (ktp * 32 + 16 + l15) * 32 + kswz);
            unsigned int mw = m[ktp];
            unsigned int mb0 = mw >> (quad * 4);
            unsigned int mb1 = mw >> (quad * 4 + 16);
#pragma unroll
            for (int e = 0; e < 4; ++e) {
                if ((mb0 >> e) & 1u) cin0[e] = NEGBIG_;
                if ((mb1 >> e) & 1u) cin1[e] = NEGBIG_;
            }
            // S^T tile: rows = keys (quad*4+e), cols = queries (l15)
            v4f s0 = __builtin_amdgcn_mfma_f32_16x16x32_f16(bf0, af, cin0, 0, 0, 0);
            v4f s1 = __builtin_amdgcn_mfma_f32_16x16x32_f16(bf1, af, cin1, 0, 0, 0);
            unsigned int u0 = pk2(__builtin_amdgcn_exp2f(s0[0]), __builtin_amdgcn_exp2f(s0[1]));
            unsigned int u1 = pk2(__builtin_amdgcn_exp2f(s0[2]), __builtin_amdgcn_exp2f(s0[3]));
            unsigned int u2 = pk2(__builtin_amdgcn_exp2f(s1[0]), __builtin_amdgcn_exp2f(s1[1]));
            unsigned int u3 = pk2(__builtin_amdgcn_exp2f(s1[2]), __builtin_amdgcn_exp2f(s1[3]));
            // P[q=l15][key 0..31]: logical block b = half*2 + (quad>>1), XOR pswz
            // b64 stores: 8B contiguous (keys quad*4..+3), bank-uniform (4 dw/bank)
            f16* pr = Pw + l15 * 32 + (quad & 1) * 4;
            *(uint2*)(pr + ((((quad >> 1) + 0) ^ pswz) << 3)) = make_uint2(u0, u1);
            *(uint2*)(pr + ((((quad >> 1) + 2) ^ pswz) << 3)) = make_uint2(u2, u3);
            v8h a = *(const v8h*)(Pw + l15 * 32 + ((quad ^ pswz) << 3));
            const f16* vt = Vts + ktp * 1024;
            v8h w0 = *(const v8h*)(vt + l15 * 32 + ((quad ^ xw) << 3));            // ch 0..15
            v8h w1 = *(const v8h*)(vt + (16 + l15) * 32 + ((quad ^ 2 ^ xw) << 3)); // ch 16..31
            // O^T: rows = ch (quad*4+e), cols = queries (l15)
            o0 = __builtin_amdgcn_mfma_f32_16x16x32_f16(w0, a, o0, 0, 0, 0);
            o1 = __builtin_amdgcn_mfma_f32_16x16x32_f16(w1, a, o1, 0, 0, 0);
            o2 = __builtin_amdgcn_mfma_f32_16x16x32_f16(ones, a, o2, 0, 0, 0);  // rsum[q]
        }
        if (q < LL) {
            float inv = 1.0f / o2[0];          // rsum for this lane's query, uniform in e
            f16* orow = ao + ((size_t)(n * LL + q)) * DIMD + h * HEADD + quad * 4;
            v4h w0, w1;
#pragma unroll
            for (int e = 0; e < 4; ++e) {
                w0[e] = (f16)(o0[e] * inv);
                w1[e] = (f16)(o1[e] * inv);
            }
            *(v4h*)(orow) = w0;
            *(v4h*)(orow + 16) = w1;
        }
    }
}

// ---------------- proj GEMM (128x128, 2-phase dbuf pipeline, XCD swizzle) ----------------
__global__ __launch_bounds__(256) void proj_gemm(
    const f16* __restrict__ ao, const f16* __restrict__ pwt,
    const float* __restrict__ pb, float* __restrict__ out) {
    __shared__ f16 ABs[16384];
    const int lin = blockIdx.x;
    const int m0 = ((lin / 24) * 8 + (lin & 7)) * 128;
    const int n0 = ((lin >> 3) % 3) * 128;
    const int tid = threadIdx.x;
    const int wave = tid >> 6, lane = tid & 63;
    const int quad = lane >> 4, l15 = lane & 15;
    const int wm = (wave >> 1) * 64, wn = (wave & 1) * 64;
    const int srow = lane >> 2, scol = (lane & 3) * 8;
    const f16* ga0 = ao + (size_t)(m0 + wave * 32 + srow) * DIMD + scol;
    const f16* ga1 = ga0 + (size_t)16 * DIMD;
    const f16* gb0 = pwt + (size_t)(n0 + wave * 32 + srow) * DIMD + scol;
    const f16* gb1 = gb0 + (size_t)16 * DIMD;
    {
        f16* la = ABs + wave * 1024;
        async_cp16(ga0, la);
        async_cp16(ga1, la + 512);
        async_cp16(gb0, la + 4096);
        async_cp16(gb1, la + 4096 + 512);
    }
    __syncthreads();
    v4f acc[4][4] = {};
    for (int t = 0; t < 12; ++t) {
        const int cur = (t & 1) << 13;
        if (t < 11) {
            const int nk = (t + 1) * 32;
            f16* la = ABs + (cur ^ 8192) + wave * 1024;
            async_cp16(ga0 + nk, la);
            async_cp16(ga1 + nk, la + 512);
            async_cp16(gb0 + nk, la + 4096);
            async_cp16(gb1 + nk, la + 4096 + 512);
        }
        const f16* As = ABs + cur;
        const f16* Bs = As + 4096;
        v8h a[4], b[4];
#pragma unroll
        for (int i = 0; i < 4; ++i) a[i] = *(const v8h*)(As + (wm + i * 16 + l15) * 32 + quad * 8);
#pragma unroll
        for (int j = 0; j < 4; ++j) b[j] = *(const v8h*)(Bs + (wn + j * 16 + l15) * 32 + quad * 8);
#pragma unroll
        for (int i = 0; i < 4; ++i)
#pragma unroll
            for (int j = 0; j < 4; ++j)
                acc[i][j] = __builtin_amdgcn_mfma_f32_16x16x32_f16(a[i], b[j], acc[i][j], 0, 0, 0);
        __syncthreads();
    }
#pragma unroll
    for (int i = 0; i < 4; ++i)
#pragma unroll
        for (int e = 0; e < 4; ++e) {
            int gm = m0 + wm + i * 16 + quad * 4 + e;
            if (gm < NTOK) {
#pragma unroll
                for (int j = 0; j < 4; ++j) {
                    int gn = n0 + wn + j * 16 + l15;
                    out[(size_t)gm * DIMD + gn] = acc[i][j][e] + pb[gn];
                }
            }
        }
}

extern "C" void kernel_launch(void* const* d_in, const int* in_sizes, int n_in,
                              void* d_out, int out_size, void* d_ws, size_t ws_size,
                              hipStream_t stream) {
    const float* x      = (const float*)d_in[0];
    const float* qkv_w  = (const float*)d_in[1];
    const float* table  = (const float*)d_in[2];
    const float* proj_w = (const float*)d_in[3];
    const float* proj_b = (const float*)d_in[4];
    const int* mask     = (const int*)d_in[5];
    const int* rel      = (const int*)d_in[6];
    float* out = (float*)d_out;
    char* ws = (char*)d_ws;

    f16* q    = (f16*)(ws + OFF_Q);
    f16* k    = (f16*)(ws + OFF_K);
    f16* v    = (f16*)(ws + OFF_V);
    f16* xh   = (f16*)(ws + OFF_AO);   // xh and ao share the [MP][384] buffer
    f16* ao   = (f16*)(ws + OFF_AO);
    float* bt = (float*)(ws + OFF_BT);
    f16* wt   = (f16*)(ws + OFF_WT);
    f16* pwt  = (f16*)(ws + OFF_PWT);
    unsigned int* mtb = (unsigned int*)(ws + OFF_MTB);

    (void)hipFuncSetAttribute((const void*)attn_kernel,
                              hipFuncAttributeMaxDynamicSharedMemorySize, SMEM_ATTN);

    prep_all<<<(SPREP + 255) / 256, 256, 0, stream>>>(
        x, xh, qkv_w, wt, proj_w, pwt, table, rel, bt, mask, mtb);
    qkv_gemm<<<dim3(MPT * 9), 256, 0, stream>>>(xh, wt, q, k, v);
    attn_kernel<<<dim3(NWW * NHH), 512, SMEM_ATTN, stream>>>(q, k, v, bt, mtb, ao);
    proj_gemm<<<dim3(MPT * 3), 256, 0, stream>>>(ao, pwt, proj_b, out);
}

// Round 8
// 200.388 us; speedup vs baseline: 1.9837x; 1.0567x over previous
//
#include <hip/hip_runtime.h>

// WindowAttention (Swin-3D) on MI355X / gfx950.
// R22 = R21 with prep_all restructured for memory-level parallelism (the new
// top dispatch at 42.5us, latency-bound: VALUBusy 7%, 20% HBM). Bias build
// now does 4 independent rel loads + 4 independent table gathers + one v4f
// store per thread (ILP 4); mask pack fully unrolled (32 loads in flight);
// x->f16 does 2 float4 loads + one 16B store. Latency-bound branches placed
// first in the grid. attn/qkv/proj byte-identical to R21 (attn: LDS-P +
// conflict-free Vts, 40 VGPR, no scratch; GEMMs: 2-phase dbuf pipeline).

#define DIMD 384
#define NHH 12
#define HEADD 32
#define LL 343
#define NWW 64
#define NTOK (NWW * LL)            // 21952
#define MPT 176                    // m tiles (128 each)
#define MP (MPT * 128)             // 22528
#define LP 352                     // L padded to 22*16
#define QT 22
#define MW 12                      // mask words per query row (11 used)
#define SCALE_ 0.17677669529663687f
#define LOG2E_ 1.4426950408889634f
#define NEGBIG_ (-1.0e4f)

typedef _Float16 f16;
typedef _Float16 v8h __attribute__((ext_vector_type(8)));
typedef _Float16 v4h __attribute__((ext_vector_type(4)));
typedef float v4f __attribute__((ext_vector_type(4)));

__device__ __forceinline__ void async_cp16(const void* g, void* l) {
    __builtin_amdgcn_global_load_lds(
        (const __attribute__((address_space(1))) void*)g,
        (__attribute__((address_space(3))) void*)l, 16, 0, 0);
}

__device__ __forceinline__ unsigned int pk2(float a, float b) {
    return __builtin_bit_cast(unsigned int, __builtin_amdgcn_cvt_pkrtz(a, b));
}

// ---- workspace layout (bytes) ----
constexpr size_t HBUF = (size_t)NHH * MP * HEADD * 2;          // per q/k/v
constexpr size_t OFF_Q    = 0;
constexpr size_t OFF_K    = OFF_Q  + HBUF;
constexpr size_t OFF_V    = OFF_K  + HBUF;
constexpr size_t OFF_AO   = OFF_V  + HBUF;                     // f16 [MP][384]; xh then AO
constexpr size_t OFF_BT   = OFF_AO + (size_t)MP * DIMD * 2;    // f32 biasT (NH,88,352,4) *log2e, key-major
constexpr size_t OFF_WT   = OFF_BT + (size_t)NHH * LP * LP * 4;
constexpr size_t OFF_PWT  = OFF_WT + (size_t)3 * DIMD * DIMD * 2;
constexpr size_t OFF_MTB  = OFF_PWT + (size_t)DIMD * DIMD * 2; // uint (NW, 352 queries, 12 key-words)

// attn LDS: Ks [352][32] + Vts [11][32][32] + Ps 8x[16][32]
constexpr int SMEM_ATTN = (LP * 32 + LP * 32 + 8 * 16 * 32) * 2;   // 53248

// ---------------- fused prep (ILP-restructured) ----------------
// branch order: bias(S3Q) -> mask(S4) -> x-conv(S0Q) -> wt(S1) -> pwt(S2)
#define S3Q (NHH * LP * LP / 4)        // 371712 threads, 4 bias elems each
#define S4  (NWW * MW * LP)            // 270336
#define S0Q (NTOK * DIMD / 8)          // 1053696 threads, 8 f32 each
#define S1  (3 * DIMD * DIMD)          // 442368
#define S2  (DIMD * DIMD)              // 147456
#define B0  (S3Q)
#define B1  (B0 + S4)
#define B2  (B1 + S0Q)
#define B3  (B2 + S1)
#define SPREP (B3 + S2)

__global__ __launch_bounds__(256) void prep_all(
    const float* __restrict__ x, f16* __restrict__ xh,
    const float* __restrict__ qkv_w, f16* __restrict__ wt,
    const float* __restrict__ proj_w, f16* __restrict__ pwt,
    const float* __restrict__ table, const int* __restrict__ rel, float* __restrict__ btf,
    const int* __restrict__ mask, unsigned int* __restrict__ mtb) {
    int t = blockIdx.x * 256 + threadIdx.x;
    if (t < B0) {
        // biasT[h][kq][col][j] = bias(h, query=col, key=kq*4+j)*log2e, pads -> -1e4
        // ILP: 4 independent rel loads, then 4 independent table gathers.
        int h = t / (88 * LP);
        int rem = t % (88 * LP);
        int kq = rem / LP, col = rem % LP;
        int idx[4];
        const int* rrow = rel + col * LL + kq * 4;
#pragma unroll
        for (int j = 0; j < 4; ++j) {
            int key = kq * 4 + j;
            idx[j] = (col < LL && key < LL) ? rrow[j] : -1;
        }
        v4f o;
#pragma unroll
        for (int j = 0; j < 4; ++j)
            o[j] = (idx[j] >= 0) ? table[(size_t)idx[j] * NHH + h] * LOG2E_ : NEGBIG_;
        *(v4f*)(btf + ((size_t)(h * 88 + kq) * LP + col) * 4) = o;
    } else if (t < B1) {
        // mtb[n][q][kw]: bit b = mask[n][query q][key kw*32+b]; fully unrolled
        int e = t - B0;
        int n = e / (MW * LP), rem = e % (MW * LP);
        int q = rem / MW, kw = rem % MW;
        unsigned int wd = 0;
        if (q < LL && kw < 11) {
            const int* mrow = mask + ((size_t)n * LL + q) * LL + kw * 32;
            if (kw < 10) {
#pragma unroll
                for (int b = 0; b < 32; ++b) wd |= mrow[b] ? (1u << b) : 0u;
            } else {        // kw == 10: keys 320..342 -> 23 valid
#pragma unroll
                for (int b = 0; b < 23; ++b) wd |= mrow[b] ? (1u << b) : 0u;
            }
        }
        mtb[((size_t)n * LP + q) * MW + kw] = wd;
    } else if (t < B2) {
        // x -> f16, 8 elems/thread, one 16B store
        int e = t - B1;
        const float4* xp = (const float4*)x + (size_t)e * 2;
        float4 va = xp[0], vb = xp[1];
        v8h o;
        o[0] = (f16)va.x; o[1] = (f16)va.y; o[2] = (f16)va.z; o[3] = (f16)va.w;
        o[4] = (f16)vb.x; o[5] = (f16)vb.y; o[6] = (f16)vb.z; o[7] = (f16)vb.w;
        *(v8h*)(xh + (size_t)e * 8) = o;
    } else if (t < B3) {
        int e = t - B2;
        int n = e / DIMD, k = e % DIMD;          // wt[n][k] = qkv_w[k][n]
        wt[e] = (f16)qkv_w[(size_t)k * (3 * DIMD) + n];
    } else if (t < SPREP) {
        int e = t - B3;
        int n = e / DIMD, k = e % DIMD;
        pwt[e] = (f16)proj_w[(size_t)k * DIMD + n];
    }
}

// ---------------- QKV GEMM (128x128, 2-phase dbuf pipeline, XCD swizzle) ----------------
__global__ __launch_bounds__(256) void qkv_gemm(
    const f16* __restrict__ xh, const f16* __restrict__ wt,
    f16* __restrict__ qb, f16* __restrict__ kb, f16* __restrict__ vb) {
    __shared__ f16 ABs[16384];       // 2 bufs x (A 128x32 + B 128x32)
    const int lin = blockIdx.x;
    const int m0 = ((lin / 72) * 8 + (lin & 7)) * 128;
    const int n0 = ((lin >> 3) % 9) * 128;
    const int tid = threadIdx.x;
    const int wave = tid >> 6, lane = tid & 63;
    const int quad = lane >> 4, l15 = lane & 15;
    const int wm = (wave >> 1) * 64, wn = (wave & 1) * 64;
    const int srow = lane >> 2, scol = (lane & 3) * 8;
    const f16* ga0 = xh + (size_t)(m0 + wave * 32 + srow) * DIMD + scol;
    const f16* ga1 = ga0 + (size_t)16 * DIMD;
    const f16* gb0 = wt + (size_t)(n0 + wave * 32 + srow) * DIMD + scol;
    const f16* gb1 = gb0 + (size_t)16 * DIMD;
    {
        f16* la = ABs + wave * 1024;
        async_cp16(ga0, la);
        async_cp16(ga1, la + 512);
        async_cp16(gb0, la + 4096);
        async_cp16(gb1, la + 4096 + 512);
    }
    __syncthreads();
    v4f acc[4][4] = {};
    for (int t = 0; t < 12; ++t) {
        const int cur = (t & 1) << 13;          // 0 / 8192 f16 flip
        if (t < 11) {                            // prefetch next tile: overlaps MFMA below
            const int nk = (t + 1) * 32;
            f16* la = ABs + (cur ^ 8192) + wave * 1024;
            async_cp16(ga0 + nk, la);
            async_cp16(ga1 + nk, la + 512);
            async_cp16(gb0 + nk, la + 4096);
            async_cp16(gb1 + nk, la + 4096 + 512);
        }
        const f16* As = ABs + cur;
        const f16* Bs = As + 4096;
        v8h a[4], b[4];
#pragma unroll
        for (int i = 0; i < 4; ++i) a[i] = *(const v8h*)(As + (wm + i * 16 + l15) * 32 + quad * 8);
#pragma unroll
        for (int j = 0; j < 4; ++j) b[j] = *(const v8h*)(Bs + (wn + j * 16 + l15) * 32 + quad * 8);
#pragma unroll
        for (int i = 0; i < 4; ++i)
#pragma unroll
            for (int j = 0; j < 4; ++j)
                acc[i][j] = __builtin_amdgcn_mfma_f32_16x16x32_f16(a[i], b[j], acc[i][j], 0, 0, 0);
        __syncthreads();                         // single barrier: drains prefetch (vmcnt0) + protects buf reuse
    }
    // epilogue: per-wave private LDS transpose, zero barriers, coalesced 16B stores
    const int t3 = n0 / DIMD;
    f16* dst = (t3 == 0) ? qb : (t3 == 1) ? kb : vb;
    const float sc = (t3 == 0) ? (SCALE_ * LOG2E_) : 1.0f;
    const int nrel = n0 - t3 * DIMD;
    f16* Cw = ABs + wave * (16 * 72);            // [16 rows][72 stride], wave-private
#pragma unroll
    for (int i = 0; i < 4; ++i) {
#pragma unroll
        for (int e = 0; e < 4; ++e)
#pragma unroll
            for (int j = 0; j < 4; ++j)
                Cw[(quad * 4 + e) * 72 + j * 16 + l15] = (f16)(acc[i][j][e] * sc);
        // same-wave DS ordering: no barrier needed
#pragma unroll
        for (int c = 0; c < 2; ++c) {
            int chunk = quad + c * 4;            // 0..7 -> 8-col piece
            int gm = m0 + wm + i * 16 + l15;
            int gcol = nrel + wn + chunk * 8;
            if (gm < NTOK) {
                size_t off = (size_t)(gcol >> 5) * ((size_t)MP * HEADD)
                           + (gcol & 31) + (size_t)gm * HEADD;
                *(v8h*)(dst + off) = *(const v8h*)(Cw + l15 * 72 + chunk * 8);
            }
        }
    }
}

// ---------------- attention (S^T tiles, reg-mask, LDS-P, new Vts, 3 blk/CU) ----------------
__global__ __launch_bounds__(512, 6) void attn_kernel(
    const f16* __restrict__ qb, const f16* __restrict__ kb, const f16* __restrict__ vb,
    const float* __restrict__ biasT, const unsigned int* __restrict__ mtb,
    f16* __restrict__ ao) {
    extern __shared__ char smem[];
    f16* Ks  = (f16*)smem;            // [352 keys][32 ch], 16B-block XOR by (key&3)
    f16* Vts = Ks + LP * 32;          // [11 ktp][32 ch][32 keys], key-block XOR by (ch>>3)&3
    f16* Ps  = Vts + LP * 32;         // 8 waves x [16 q][32 keys], block XOR by ((l15>>1)&3)
    const int bid = blockIdx.x;
    // XCD-chunked swizzle: XCD x owns j2 in [96x, 96x+96) -> 1.5 head slices per XCD L2
    const int j2 = (bid & 7) * 96 + (bid >> 3);
    const int n = j2 & 63, h = j2 >> 6;
    const int tid = threadIdx.x, wave = tid >> 6, lane = tid & 63;
    const int quad = lane >> 4, l15 = lane & 15;
    const size_t slice = ((size_t)h * MP + n * LL) * HEADD;
    const f16* qg = qb + slice;
    const f16* kg = kb + slice;
    const f16* vg = vb + slice;
    // K staging: [key][32ch], swizzled 16B blocks, zero-pad keys >= LL
    for (int i = tid; i < LP * 4; i += 512) {
        int row = i >> 2, c8 = i & 3;
        v8h vv = {};
        if (row < LL) vv = *(const v8h*)(kg + (size_t)i * 8);
        *(v8h*)(Ks + row * 32 + ((c8 ^ (row & 3)) << 3)) = vv;
    }
    // V^T staging: [ktp][ch][key32], key-block XOR by (ch>>3)&3
    for (int i = tid; i < LP * 4; i += 512) {
        int key = i >> 2, c8 = i & 3;
        v8h vv = {};
        if (key < LL) vv = *(const v8h*)(vg + (size_t)key * HEADD + c8 * 8);
        int kk = key & 31;
        f16* d = Vts + (key >> 5) * 1024 + ((((kk >> 3) ^ c8) & 3) << 3) + (kk & 7);
#pragma unroll
        for (int j = 0; j < 8; ++j) d[(c8 * 8 + j) * 32] = vv[j];
    }
    __syncthreads();
    f16* Pw = Ps + wave * (16 * 32);
    const float* bh = biasT + (size_t)h * LP * LP;     // [88 key-quads][352 q][4]
    const unsigned int* mg = mtb + (size_t)n * LP * MW;
    const v8h ones = {(f16)1.f, (f16)1.f, (f16)1.f, (f16)1.f,
                      (f16)1.f, (f16)1.f, (f16)1.f, (f16)1.f};
    const int pswz = (l15 >> 1) & 3;
    const int kswz = (quad ^ (l15 & 3)) << 3;
    const int xw = (l15 >> 3) & 1;
    for (int qt = wave; qt < QT; qt += 8) {
        const int q = qt * 16 + l15;
        v8h af = *(const v8h*)(qg + (size_t)q * HEADD + quad * 8);      // Q[q][ch]
        uint4 mA = *(const uint4*)(mg + q * MW);
        uint4 mB = *(const uint4*)(mg + q * MW + 4);
        uint4 mC = *(const uint4*)(mg + q * MW + 8);
        unsigned int m[12] = {mA.x, mA.y, mA.z, mA.w, mB.x, mB.y, mB.z, mB.w,
                              mC.x, mC.y, mC.z, mC.w};
        const float* bq = bh + (size_t)q * 4;
        v4f cinN[2];
        cinN[0] = *(const v4f*)(bq + (size_t)(quad) * (LP * 4));
        cinN[1] = *(const v4f*)(bq + (size_t)(4 + quad) * (LP * 4));
        v4f o0 = {}, o1 = {}, o2 = {};
#pragma unroll
        for (int ktp = 0; ktp < 11; ++ktp) {
            v4f cin0 = cinN[0], cin1 = cinN[1];
            if (ktp < 10) {   // depth-1 prefetch: overlaps this tile's exp/PV
                cinN[0] = *(const v4f*)(bq + (size_t)((ktp + 1) * 8 + quad) * (LP * 4));
                cinN[1] = *(const v4f*)(bq + (size_t)((ktp + 1) * 8 + 4 + quad) * (LP * 4));
            }
            v8h bf0 = *(const v8h*)(Ks + (ktp * 32 + l15) * 32 + kswz);
            v8h bf1 = *(const v8h*)(Ks + (ktp * 32 + 16 + l15) * 32 + kswz);
            unsigned int mw = m[ktp];
            unsigned int mb0 = mw >> (quad * 4);
            unsigned int mb1 = mw >> (quad * 4 + 16);
#pragma unroll
            for (int e = 0; e < 4; ++e) {
                if ((mb0 >> e) & 1u) cin0[e] = NEGBIG_;
                if ((mb1 >> e) & 1u) cin1[e] = NEGBIG_;
            }
            // S^T tile: rows = keys (quad*4+e), cols = queries (l15)
            v4f s0 = __builtin_amdgcn_mfma_f32_16x16x32_f16(bf0, af, cin0, 0, 0, 0);
            v4f s1 = __builtin_amdgcn_mfma_f32_16x16x32_f16(bf1, af, cin1, 0, 0, 0);
            unsigned int u0 = pk2(__builtin_amdgcn_exp2f(s0[0]), __builtin_amdgcn_exp2f(s0[1]));
            unsigned int u1 = pk2(__builtin_amdgcn_exp2f(s0[2]), __builtin_amdgcn_exp2f(s0[3]));
            unsigned int u2 = pk2(__builtin_amdgcn_exp2f(s1[0]), __builtin_amdgcn_exp2f(s1[1]));
            unsigned int u3 = pk2(__builtin_amdgcn_exp2f(s1[2]), __builtin_amdgcn_exp2f(s1[3]));
            // P[q=l15][key 0..31]: logical block b = half*2 + (quad>>1), XOR pswz
            // b64 stores: 8B contiguous (keys quad*4..+3), bank-uniform (4 dw/bank)
            f16* pr = Pw + l15 * 32 + (quad & 1) * 4;
            *(uint2*)(pr + ((((quad >> 1) + 0) ^ pswz) << 3)) = make_uint2(u0, u1);
            *(uint2*)(pr + ((((quad >> 1) + 2) ^ pswz) << 3)) = make_uint2(u2, u3);
            v8h a = *(const v8h*)(Pw + l15 * 32 + ((quad ^ pswz) << 3));
            const f16* vt = Vts + ktp * 1024;
            v8h w0 = *(const v8h*)(vt + l15 * 32 + ((quad ^ xw) << 3));            // ch 0..15
            v8h w1 = *(const v8h*)(vt + (16 + l15) * 32 + ((quad ^ 2 ^ xw) << 3)); // ch 16..31
            // O^T: rows = ch (quad*4+e), cols = queries (l15)
            o0 = __builtin_amdgcn_mfma_f32_16x16x32_f16(w0, a, o0, 0, 0, 0);
            o1 = __builtin_amdgcn_mfma_f32_16x16x32_f16(w1, a, o1, 0, 0, 0);
            o2 = __builtin_amdgcn_mfma_f32_16x16x32_f16(ones, a, o2, 0, 0, 0);  // rsum[q]
        }
        if (q < LL) {
            float inv = 1.0f / o2[0];          // rsum for this lane's query, uniform in e
            f16* orow = ao + ((size_t)(n * LL + q)) * DIMD + h * HEADD + quad * 4;
            v4h w0, w1;
#pragma unroll
            for (int e = 0; e < 4; ++e) {
                w0[e] = (f16)(o0[e] * inv);
                w1[e] = (f16)(o1[e] * inv);
            }
            *(v4h*)(orow) = w0;
            *(v4h*)(orow + 16) = w1;
        }
    }
}

// ---------------- proj GEMM (128x128, 2-phase dbuf pipeline, XCD swizzle) ----------------
__global__ __launch_bounds__(256) void proj_gemm(
    const f16* __restrict__ ao, const f16* __restrict__ pwt,
    const float* __restrict__ pb, float* __restrict__ out) {
    __shared__ f16 ABs[16384];
    const int lin = blockIdx.x;
    const int m0 = ((lin / 24) * 8 + (lin & 7)) * 128;
    const int n0 = ((lin >> 3) % 3) * 128;
    const int tid = threadIdx.x;
    const int wave = tid >> 6, lane = tid & 63;
    const int quad = lane >> 4, l15 = lane & 15;
    const int wm = (wave >> 1) * 64, wn = (wave & 1) * 64;
    const int srow = lane >> 2, scol = (lane & 3) * 8;
    const f16* ga0 = ao + (size_t)(m0 + wave * 32 + srow) * DIMD + scol;
    const f16* ga1 = ga0 + (size_t)16 * DIMD;
    const f16* gb0 = pwt + (size_t)(n0 + wave * 32 + srow) * DIMD + scol;
    const f16* gb1 = gb0 + (size_t)16 * DIMD;
    {
        f16* la = ABs + wave * 1024;
        async_cp16(ga0, la);
        async_cp16(ga1, la + 512);
        async_cp16(gb0, la + 4096);
        async_cp16(gb1, la + 4096 + 512);
    }
    __syncthreads();
    v4f acc[4][4] = {};
    for (int t = 0; t < 12; ++t) {
        const int cur = (t & 1) << 13;
        if (t < 11) {
            const int nk = (t + 1) * 32;
            f16* la = ABs + (cur ^ 8192) + wave * 1024;
            async_cp16(ga0 + nk, la);
            async_cp16(ga1 + nk, la + 512);
            async_cp16(gb0 + nk, la + 4096);
            async_cp16(gb1 + nk, la + 4096 + 512);
        }
        const f16* As = ABs + cur;
        const f16* Bs = As + 4096;
        v8h a[4], b[4];
#pragma unroll
        for (int i = 0; i < 4; ++i) a[i] = *(const v8h*)(As + (wm + i * 16 + l15) * 32 + quad * 8);
#pragma unroll
        for (int j = 0; j < 4; ++j) b[j] = *(const v8h*)(Bs + (wn + j * 16 + l15) * 32 + quad * 8);
#pragma unroll
        for (int i = 0; i < 4; ++i)
#pragma unroll
            for (int j = 0; j < 4; ++j)
                acc[i][j] = __builtin_amdgcn_mfma_f32_16x16x32_f16(a[i], b[j], acc[i][j], 0, 0, 0);
        __syncthreads();
    }
#pragma unroll
    for (int i = 0; i < 4; ++i)
#pragma unroll
        for (int e = 0; e < 4; ++e) {
            int gm = m0 + wm + i * 16 + quad * 4 + e;
            if (gm < NTOK) {
#pragma unroll
                for (int j = 0; j < 4; ++j) {
                    int gn = n0 + wn + j * 16 + l15;
                    out[(size_t)gm * DIMD + gn] = acc[i][j][e] + pb[gn];
                }
            }
        }
}

extern "C" void kernel_launch(void* const* d_in, const int* in_sizes, int n_in,
                              void* d_out, int out_size, void* d_ws, size_t ws_size,
                              hipStream_t stream) {
    const float* x      = (const float*)d_in[0];
    const float* qkv_w  = (const float*)d_in[1];
    const float* table  = (const float*)d_in[2];
    const float* proj_w = (const float*)d_in[3];
    const float* proj_b = (const float*)d_in[4];
    const int* mask     = (const int*)d_in[5];
    const int* rel      = (const int*)d_in[6];
    float* out = (float*)d_out;
    char* ws = (char*)d_ws;

    f16* q    = (f16*)(ws + OFF_Q);
    f16* k    = (f16*)(ws + OFF_K);
    f16* v    = (f16*)(ws + OFF_V);
    f16* xh   = (f16*)(ws + OFF_AO);   // xh and ao share the [MP][384] buffer
    f16* ao   = (f16*)(ws + OFF_AO);
    float* bt = (float*)(ws + OFF_BT);
    f16* wt   = (f16*)(ws + OFF_WT);
    f16* pwt  = (f16*)(ws + OFF_PWT);
    unsigned int* mtb = (unsigned int*)(ws + OFF_MTB);

    (void)hipFuncSetAttribute((const void*)attn_kernel,
                              hipFuncAttributeMaxDynamicSharedMemorySize, SMEM_ATTN);

    prep_all<<<(SPREP + 255) / 256, 256, 0, stream>>>(
        x, xh, qkv_w, wt, proj_w, pwt, table, rel, bt, mask, mtb);
    qkv_gemm<<<dim3(MPT * 9), 256, 0, stream>>>(xh, wt, q, k, v);
    attn_kernel<<<dim3(NWW * NHH), 512, SMEM_ATTN, stream>>>(q, k, v, bt, mtb, ao);
    proj_gemm<<<dim3(MPT * 3), 256, 0, stream>>>(ao, pwt, proj_b, out);
}